// Round 6
// baseline (352.461 us; speedup 1.0000x reference)
//
#include <hip/hip_runtime.h>
#include <hip/hip_bf16.h>
#include <cstdint>
#include <cstddef>

typedef __attribute__((ext_vector_type(8))) short bf16x8;
typedef __attribute__((ext_vector_type(4))) float floatx4;

#define BATCH 4
#define SEQ   2048
#define EMBD  1024
#define HEADS 16
#define HD    64
#define NTOK  (BATCH*SEQ)
#define QSCALE 0.18033688f  // log2(e)/sqrt(64)

__device__ __forceinline__ short f2bs(float f) {
  union { __hip_bfloat16 b; short s; } u;
  u.b = __float2bfloat16(f);   // RNE
  return u.s;
}

// 8 f32 -> bf16x8 with RNE (precast path)
__device__ __forceinline__ bf16x8 load8f(const float* p) {
  const float4* q = (const float4*)p;
  float4 a = q[0], b = q[1];
  bf16x8 r;
  r[0] = f2bs(a.x); r[1] = f2bs(a.y); r[2] = f2bs(a.z); r[3] = f2bs(a.w);
  r[4] = f2bs(b.x); r[5] = f2bs(b.y); r[6] = f2bs(b.z); r[7] = f2bs(b.w);
  return r;
}

// pack two f32 -> two bf16 (truncation) in one v_perm: low16 = lo, high16 = hi
__device__ __forceinline__ unsigned pack_trunc(float lo, float hi) {
  return __builtin_amdgcn_perm(__float_as_uint(hi), __float_as_uint(lo), 0x07060302u);
}

// async global->LDS, 16B per lane; LDS dest = wave-uniform base + lane*16
__device__ __forceinline__ void async16(const __hip_bfloat16* g, __hip_bfloat16* l) {
  __builtin_amdgcn_global_load_lds(
      (const __attribute__((address_space(1))) unsigned int*)g,
      (__attribute__((address_space(3))) unsigned int*)l, 16, 0, 0);
}

// ---------------------------------------------------------------------------
// precast: f32 -> bf16 for embedding + 4 weight matrices (one launch)
// ---------------------------------------------------------------------------
__global__ __launch_bounds__(256)
void precast(const float* __restrict__ e,  const float* __restrict__ wq,
             const float* __restrict__ wk, const float* __restrict__ wv,
             const float* __restrict__ wo,
             __hip_bfloat16* __restrict__ eB,  __hip_bfloat16* __restrict__ wqB,
             __hip_bfloat16* __restrict__ wkB, __hip_bfloat16* __restrict__ wvB,
             __hip_bfloat16* __restrict__ woB)
{
  int blk = blockIdx.x;
  const float* src; __hip_bfloat16* dst; int base;
  if      (blk < 4096) { src = e;  dst = eB;  base = 0;    }
  else if (blk < 4608) { src = wq; dst = wqB; base = 4096; }
  else if (blk < 5120) { src = wk; dst = wkB; base = 4608; }
  else if (blk < 5632) { src = wv; dst = wvB; base = 5120; }
  else                 { src = wo; dst = woB; base = 5632; }
  size_t idx = ((size_t)(blk - base)*256 + threadIdx.x) * 8;
  *(bf16x8*)(dst + idx) = load8f(src + idx);
}

// ---------------------------------------------------------------------------
// bf16 GEMM core (m97 structure): acc += A[tm..+128,:] @ W[tn..+128,:]^T
// LDS [128][64] unpadded, XOR-swizzled (slot c' holds col c = c' ^ (row&7)).
// ---------------------------------------------------------------------------
__device__ __forceinline__ void gemm_bf16_core(
    const __hip_bfloat16* __restrict__ A,
    const __hip_bfloat16* __restrict__ W,
    __hip_bfloat16* sA, __hip_bfloat16* sB,
    floatx4 (&acc)[4][4], int tm, int tn)
{
  const int tid = threadIdx.x;
  const int wid = tid >> 6, lane = tid & 63;
  const int wm = (wid >> 1) * 64, wn = (wid & 1) * 64;
  const int m16 = lane & 15, q = lane >> 4;
  const int lr = lane >> 3;              // row within 8-row chunk
  const int lc = (lane & 7) ^ lr;        // swizzled source col16

  for (int k0 = 0; k0 < EMBD; k0 += 64) {
    #pragma unroll
    for (int c2 = 0; c2 < 4; ++c2) {
      int c = wid*4 + c2;
      int row = c*8 + lr;
      async16(A + (size_t)(tm + row)*EMBD + k0 + lc*8, sA + c*512);
      async16(W + (size_t)(tn + row)*EMBD + k0 + lc*8, sB + c*512);
    }
    __syncthreads();
    #pragma unroll
    for (int ks = 0; ks < 2; ++ks) {
      bf16x8 af[4], bfr[4];
      #pragma unroll
      for (int i = 0; i < 4; ++i)
        af[i] = *(const bf16x8*)&sA[(wm + i*16 + m16)*64 + ((ks*4 + q) ^ (m16 & 7))*8];
      #pragma unroll
      for (int j = 0; j < 4; ++j)
        bfr[j] = *(const bf16x8*)&sB[(wn + j*16 + m16)*64 + ((ks*4 + q) ^ (m16 & 7))*8];
      #pragma unroll
      for (int i = 0; i < 4; ++i)
        #pragma unroll
        for (int j = 0; j < 4; ++j)
          acc[i][j] = __builtin_amdgcn_mfma_f32_16x16x32_bf16(af[i], bfr[j], acc[i][j], 0, 0, 0);
    }
    __syncthreads();
  }
}

// ---------------------------------------------------------------------------
// QKV projection (bf16 in): z=0 -> Q*QSCALE [bh][s][d], z=1 -> K [bh][s][d],
// z=2 -> V^T [bh][d][s]. Each block processes TWO adjacent m-tiles so the
// grid is 768 = 3 blocks/CU exactly (single dispatch phase; 1536 with 5/CU
// capacity had a guaranteed 1280+256 two-phase tail).
// ---------------------------------------------------------------------------
__global__ __launch_bounds__(256)
void gemm_qkv(const __hip_bfloat16* __restrict__ A,
              const __hip_bfloat16* __restrict__ W0, const float* __restrict__ b0, __hip_bfloat16* __restrict__ C0,
              const __hip_bfloat16* __restrict__ W1, const float* __restrict__ b1, __hip_bfloat16* __restrict__ C1,
              const __hip_bfloat16* __restrict__ W2, const float* __restrict__ b2, __hip_bfloat16* __restrict__ C2)
{
  __shared__ __hip_bfloat16 sA[128*64];
  __shared__ __hip_bfloat16 sB[128*64];
  const int z = blockIdx.z;
  const __hip_bfloat16* W = (z == 0) ? W0 : (z == 1) ? W1 : W2;
  const float* bias       = (z == 0) ? b0 : (z == 1) ? b1 : b2;
  __hip_bfloat16* C       = (z == 0) ? C0 : (z == 1) ? C1 : C2;

  const int tid = threadIdx.x, wid = tid >> 6, lane = tid & 63;
  const int wm = (wid >> 1) * 64, wn = (wid & 1) * 64;
  const int m16 = lane & 15, q = lane >> 4;
  const int tn = blockIdx.y * 128;

  for (int mi = 0; mi < 2; ++mi) {
    const int tm = (blockIdx.x * 2 + mi) * 128;
    floatx4 acc[4][4] = {};
    gemm_bf16_core(A, W, sA, sB, acc, tm, tn);

    if (z < 2) {
      const float sc = (z == 0) ? QSCALE : 1.0f;
      #pragma unroll
      for (int i = 0; i < 4; ++i)
        #pragma unroll
        for (int j = 0; j < 4; ++j)
          #pragma unroll
          for (int r = 0; r < 4; ++r) {
            int gm = tm + wm + i*16 + q*4 + r;     // token
            int gn = tn + wn + j*16 + m16;         // feature
            float v = (acc[i][j][r] + bias[gn]) * sc;
            int b = gm >> 11, s = gm & (SEQ - 1);
            int h = gn >> 6,  d = gn & (HD - 1);
            size_t bh = (size_t)(b*HEADS + h);
            C[(bh*SEQ + s)*HD + d] = __float2bfloat16(v);
          }
    } else {
      #pragma unroll
      for (int i = 0; i < 4; ++i)
        #pragma unroll
        for (int j = 0; j < 4; ++j) {
          int gm0 = tm + wm + i*16 + q*4;          // first token of quad
          int gn  = tn + wn + j*16 + m16;
          float bv = bias[gn];
          int b = gm0 >> 11, s0 = gm0 & (SEQ - 1);
          int h = gn >> 6,  d = gn & (HD - 1);
          size_t bh = (size_t)(b*HEADS + h);
          short4 pk;
          pk.x = f2bs(acc[i][j][0] + bv);
          pk.y = f2bs(acc[i][j][1] + bv);
          pk.z = f2bs(acc[i][j][2] + bv);
          pk.w = f2bs(acc[i][j][3] + bv);
          *(short4*)&C[(bh*HD + d)*SEQ + s0] = pk;  // V^T: 4 consecutive s
        }
    }
  }
}

// ---------------------------------------------------------------------------
// Output projection: A (bf16 attn out) @ Wo^T + bo -> f32 d_out
// ---------------------------------------------------------------------------
__global__ __launch_bounds__(256)
void gemm_outp(const __hip_bfloat16* __restrict__ A,
               const __hip_bfloat16* __restrict__ W, const float* __restrict__ bias,
               float* __restrict__ C)
{
  __shared__ __hip_bfloat16 sA[128*64];
  __shared__ __hip_bfloat16 sB[128*64];
  const int tm = blockIdx.x * 128, tn = blockIdx.y * 128;
  floatx4 acc[4][4] = {};
  gemm_bf16_core(A, W, sA, sB, acc, tm, tn);
  const int tid = threadIdx.x, wid = tid >> 6, lane = tid & 63;
  const int wm = (wid >> 1) * 64, wn = (wid & 1) * 64;
  const int m16 = lane & 15, q = lane >> 4;
  #pragma unroll
  for (int i = 0; i < 4; ++i)
    #pragma unroll
    for (int j = 0; j < 4; ++j)
      #pragma unroll
      for (int r = 0; r < 4; ++r) {
        int gm = tm + wm + i*16 + q*4 + r;
        int gn = tn + wn + j*16 + m16;
        C[(size_t)gm*EMBD + gn] = acc[i][j][r] + bias[gn];
      }
}

// ---------------------------------------------------------------------------
// Flash attention, no-max softmax (scores bounded ~|2.5|; Q pre-scaled by
// log2(e)/8 so p = 2^score). Q-tile = 128 rows (2 q-sets of 16 per wave),
// Q fragments in registers, K/V^T double-buffered (one barrier per tile),
// V^T fragments register-hoisted & shared, l via ones-column MFMA, P packed
// by v_perm truncation into an XOR-swizzled unpadded sP.
// LDS = 16K(sK) + 16K(sVT) + 8K(sP) = 40960 B -> exactly 4 blocks/CU;
// grid 1024 = 256 CU x 4 -> single dispatch phase.
// Block index XCD-swizzled: all 16 q-tiles of one bh on one XCD (K/V L2 reuse).
// ---------------------------------------------------------------------------
__global__ __launch_bounds__(256)
void attn_fused(const __hip_bfloat16* __restrict__ Q,
                const __hip_bfloat16* __restrict__ Km,
                const __hip_bfloat16* __restrict__ Vt,
                __hip_bfloat16* __restrict__ O)
{
  __shared__ __hip_bfloat16 sK[2][64*64], sVT[2][64*64];
  __shared__ __hip_bfloat16 sP[4][16*64];
  const int tid = threadIdx.x, wid = tid >> 6, lane = tid & 63;
  const int m16 = lane & 15, g = lane >> 4;
  const int lr = lane >> 3;              // staging row-within-chunk
  const int lc = (lane & 7) ^ lr;        // swizzled source col16
  // XCD-aware mapping: XCD = blockIdx.x % 8 (round-robin heuristic);
  // bh constant per (x&7, x>>7) -> one bh's 16 q-tiles share an XCD.
  const int qt = (blockIdx.x >> 3) & 15;
  const int bh = (blockIdx.x & 7) | ((blockIdx.x >> 7) << 3);
  const int b = bh >> 4, h = bh & (HEADS - 1);
  const int swz = (m16 & 7);

  const __hip_bfloat16* Qb = Q  + ((size_t)bh*SEQ + qt*128) * HD;
  const __hip_bfloat16* Kb = Km + (size_t)bh*SEQ*HD;
  const __hip_bfloat16* Vb = Vt + (size_t)bh*HD*SEQ;

  // Q fragments straight from global (B-operand layout: n=m16, k=g*8+j)
  bf16x8 qf[2][2];
  #pragma unroll
  for (int u = 0; u < 2; ++u)
    #pragma unroll
    for (int ks = 0; ks < 2; ++ks)
      qf[u][ks] = *(const bf16x8*)(Qb + (size_t)(u*64 + wid*16 + m16)*HD + ks*32 + g*8);

  bf16x8 onesf;
  #pragma unroll
  for (int i = 0; i < 8; ++i) onesf[i] = (short)0x3F80;   // bf16 1.0

  floatx4 o_acc[2][4] = {};
  floatx4 lacc[2] = {};

  #define STAGE(KT, BUF)                                                     \
    { int _c = wid*2;                                                        \
      _Pragma("unroll")                                                      \
      for (int c2 = 0; c2 < 2; ++c2) {                                       \
        int c = _c + c2, row = c*8 + lr;                                     \
        async16(Kb + (size_t)((KT)*64 + row)*HD + lc*8, sK[BUF] + c*512);    \
        async16(Vb + (size_t)row*SEQ + (KT)*64 + lc*8,  sVT[BUF] + c*512);   \
      } }

  STAGE(0, 0)

  for (int kt = 0; kt < SEQ/64; ++kt) {
    const int cur = kt & 1;
    __syncthreads();                 // drains prefetch(kt); guards buf reuse
    if (kt < SEQ/64 - 1) STAGE(kt + 1, cur ^ 1)

    // hoist V^T fragments (shared by both q-sets)
    bf16x8 vtf[2][4];
    #pragma unroll
    for (int ks = 0; ks < 2; ++ks)
      #pragma unroll
      for (int dt = 0; dt < 4; ++dt)
        vtf[ks][dt] = *(const bf16x8*)&sVT[cur][(dt*16 + m16)*64 + ((ks*4 + g) ^ swz)*8];

    // S^T for both q-sets, sharing K fragment loads
    floatx4 st[2][4] = {};
    #pragma unroll
    for (int ks = 0; ks < 2; ++ks) {
      #pragma unroll
      for (int nt = 0; nt < 4; ++nt) {
        bf16x8 kf = *(const bf16x8*)&sK[cur][(nt*16 + m16)*64 + ((ks*4 + g) ^ swz)*8];
        st[0][nt] = __builtin_amdgcn_mfma_f32_16x16x32_bf16(kf, qf[0][ks], st[0][nt], 0, 0, 0);
        st[1][nt] = __builtin_amdgcn_mfma_f32_16x16x32_bf16(kf, qf[1][ks], st[1][nt], 0, 0, 0);
      }
    }

    // per q-set: exp, pack, swizzled-sP round-trip, PV + l
    #pragma unroll
    for (int u = 0; u < 2; ++u) {
      #pragma unroll
      for (int nt = 0; nt < 4; ++nt) {
        float p0 = __builtin_amdgcn_exp2f(st[u][nt][0]);
        float p1 = __builtin_amdgcn_exp2f(st[u][nt][1]);
        float p2 = __builtin_amdgcn_exp2f(st[u][nt][2]);
        float p3 = __builtin_amdgcn_exp2f(st[u][nt][3]);
        uint2 pu;
        pu.x = pack_trunc(p0, p1);
        pu.y = pack_trunc(p2, p3);
        // data cols nt*16+g*4..+3 -> chunk = nt*2 + (g>>1), half = g&1
        *(uint2*)&sP[wid][m16*64 + (((nt*2 + (g>>1)) ^ swz)*8) + (g&1)*4] = pu;
      }
      #pragma unroll
      for (int ks = 0; ks < 2; ++ks) {
        // data cols ks*32+g*8..+7 -> chunk = ks*4 + g
        bf16x8 af = *(const bf16x8*)&sP[wid][m16*64 + ((ks*4 + g) ^ swz)*8];
        lacc[u] = __builtin_amdgcn_mfma_f32_16x16x32_bf16(af, onesf, lacc[u], 0, 0, 0);
        #pragma unroll
        for (int dt = 0; dt < 4; ++dt)
          o_acc[u][dt] = __builtin_amdgcn_mfma_f32_16x16x32_bf16(af, vtf[ks][dt], o_acc[u][dt], 0, 0, 0);
      }
    }
  }

  // epilogue: normalize, store [token][emb]
  #pragma unroll
  for (int u = 0; u < 2; ++u) {
    float inv[4];
    #pragma unroll
    for (int r = 0; r < 4; ++r) inv[r] = 1.0f / lacc[u][r];
    #pragma unroll
    for (int dt = 0; dt < 4; ++dt)
      #pragma unroll
      for (int r = 0; r < 4; ++r) {
        int s = qt*128 + u*64 + wid*16 + g*4 + r;
        int d = dt*16 + m16;
        float v = o_acc[u][dt][r] * inv[r];
        O[((size_t)(b*SEQ + s))*EMBD + h*HD + d] = __float2bfloat16(v);
      }
  }
}

// ---------------------------------------------------------------------------
extern "C" void kernel_launch(void* const* d_in, const int* in_sizes, int n_in,
                              void* d_out, int out_size, void* d_ws, size_t ws_size,
                              hipStream_t stream) {
  const float* emb = (const float*)d_in[0];
  const float* Wq  = (const float*)d_in[1];
  const float* bq  = (const float*)d_in[2];
  const float* Wk  = (const float*)d_in[3];
  const float* bk  = (const float*)d_in[4];
  const float* Wv  = (const float*)d_in[5];
  const float* bv  = (const float*)d_in[6];
  const float* Wo  = (const float*)d_in[7];
  const float* bo  = (const float*)d_in[8];

  const size_t T = (size_t)NTOK*EMBD;     // 8388608
  const size_t WN = (size_t)EMBD*EMBD;    // 1048576
  __hip_bfloat16* Qw  = (__hip_bfloat16*)d_ws;   // [bh][s][d], pre-scaled
  __hip_bfloat16* Kw  = Qw + T;                  // [bh][s][d]
  __hip_bfloat16* Vw  = Kw + T;                  // [bh][d][s]
  __hip_bfloat16* Aw  = Vw + T;                  // attn out [token][emb]; embB aliases (emb dead after qkv)
  __hip_bfloat16* embB = Aw;
  __hip_bfloat16* WqB = Aw + T;
  __hip_bfloat16* WkB = WqB + WN;
  __hip_bfloat16* WvB = WkB + WN;
  __hip_bfloat16* WoB = WvB + WN;
  float* Ob = (float*)d_out;

  precast<<<dim3(6144), 256, 0, stream>>>(emb, Wq, Wk, Wv, Wo,
                                          embB, WqB, WkB, WvB, WoB);

  dim3 gq(NTOK/256, EMBD/128, 3);
  gemm_qkv<<<gq, 256, 0, stream>>>(embB, WqB, bq, Qw, WkB, bk, Kw, WvB, bv, Vw);

  attn_fused<<<dim3(64*16), 256, 0, stream>>>(Qw, Kw, Vw, Aw);

  dim3 go(NTOK/128, EMBD/128);
  gemm_outp<<<go, 256, 0, stream>>>(Aw, WoB, bo, Ob);
}

// Round 7
// 294.679 us; speedup vs baseline: 1.1961x; 1.1961x over previous
//
#include <hip/hip_runtime.h>
#include <hip/hip_bf16.h>
#include <cstdint>
#include <cstddef>

typedef __attribute__((ext_vector_type(8))) short bf16x8;
typedef __attribute__((ext_vector_type(4))) float floatx4;

#define BATCH 4
#define SEQ   2048
#define EMBD  1024
#define HEADS 16
#define HD    64
#define NTOK  (BATCH*SEQ)
#define QSCALE 0.18033688f  // log2(e)/sqrt(64)

__device__ __forceinline__ short f2bs(float f) {
  union { __hip_bfloat16 b; short s; } u;
  u.b = __float2bfloat16(f);   // RNE
  return u.s;
}

// 8 f32 -> bf16x8 with RNE (precast path)
__device__ __forceinline__ bf16x8 load8f(const float* p) {
  const float4* q = (const float4*)p;
  float4 a = q[0], b = q[1];
  bf16x8 r;
  r[0] = f2bs(a.x); r[1] = f2bs(a.y); r[2] = f2bs(a.z); r[3] = f2bs(a.w);
  r[4] = f2bs(b.x); r[5] = f2bs(b.y); r[6] = f2bs(b.z); r[7] = f2bs(b.w);
  return r;
}

// pack two f32 -> two bf16 (truncation) in one v_perm: low16 = lo, high16 = hi
__device__ __forceinline__ unsigned pack_trunc(float lo, float hi) {
  return __builtin_amdgcn_perm(__float_as_uint(hi), __float_as_uint(lo), 0x07060302u);
}

// async global->LDS, 16B per lane; LDS dest = wave-uniform base + lane*16
__device__ __forceinline__ void async16(const __hip_bfloat16* g, __hip_bfloat16* l) {
  __builtin_amdgcn_global_load_lds(
      (const __attribute__((address_space(1))) unsigned int*)g,
      (__attribute__((address_space(3))) unsigned int*)l, 16, 0, 0);
}

// ---------------------------------------------------------------------------
// precast: f32 -> bf16 for embedding + 4 weight matrices (one launch)
// ---------------------------------------------------------------------------
__global__ __launch_bounds__(256)
void precast(const float* __restrict__ e,  const float* __restrict__ wq,
             const float* __restrict__ wk, const float* __restrict__ wv,
             const float* __restrict__ wo,
             __hip_bfloat16* __restrict__ eB,  __hip_bfloat16* __restrict__ wqB,
             __hip_bfloat16* __restrict__ wkB, __hip_bfloat16* __restrict__ wvB,
             __hip_bfloat16* __restrict__ woB)
{
  int blk = blockIdx.x;
  const float* src; __hip_bfloat16* dst; int base;
  if      (blk < 4096) { src = e;  dst = eB;  base = 0;    }
  else if (blk < 4608) { src = wq; dst = wqB; base = 4096; }
  else if (blk < 5120) { src = wk; dst = wkB; base = 4608; }
  else if (blk < 5632) { src = wv; dst = wvB; base = 5120; }
  else                 { src = wo; dst = woB; base = 5632; }
  size_t idx = ((size_t)(blk - base)*256 + threadIdx.x) * 8;
  *(bf16x8*)(dst + idx) = load8f(src + idx);
}

// ---------------------------------------------------------------------------
// bf16 GEMM core (m97 structure): acc += A[tm..+128,:] @ W[tn..+128,:]^T
// LDS [128][64] unpadded, XOR-swizzled (slot c' holds col c = c' ^ (row&7)).
// ---------------------------------------------------------------------------
__device__ __forceinline__ void gemm_bf16_core(
    const __hip_bfloat16* __restrict__ A,
    const __hip_bfloat16* __restrict__ W,
    __hip_bfloat16* sA, __hip_bfloat16* sB,
    floatx4 (&acc)[4][4], int tm, int tn)
{
  const int tid = threadIdx.x;
  const int wid = tid >> 6, lane = tid & 63;
  const int wm = (wid >> 1) * 64, wn = (wid & 1) * 64;
  const int m16 = lane & 15, q = lane >> 4;
  const int lr = lane >> 3;              // row within 8-row chunk
  const int lc = (lane & 7) ^ lr;        // swizzled source col16

  for (int k0 = 0; k0 < EMBD; k0 += 64) {
    #pragma unroll
    for (int c2 = 0; c2 < 4; ++c2) {
      int c = wid*4 + c2;
      int row = c*8 + lr;
      async16(A + (size_t)(tm + row)*EMBD + k0 + lc*8, sA + c*512);
      async16(W + (size_t)(tn + row)*EMBD + k0 + lc*8, sB + c*512);
    }
    __syncthreads();
    #pragma unroll
    for (int ks = 0; ks < 2; ++ks) {
      bf16x8 af[4], bfr[4];
      #pragma unroll
      for (int i = 0; i < 4; ++i)
        af[i] = *(const bf16x8*)&sA[(wm + i*16 + m16)*64 + ((ks*4 + q) ^ (m16 & 7))*8];
      #pragma unroll
      for (int j = 0; j < 4; ++j)
        bfr[j] = *(const bf16x8*)&sB[(wn + j*16 + m16)*64 + ((ks*4 + q) ^ (m16 & 7))*8];
      #pragma unroll
      for (int i = 0; i < 4; ++i)
        #pragma unroll
        for (int j = 0; j < 4; ++j)
          acc[i][j] = __builtin_amdgcn_mfma_f32_16x16x32_bf16(af[i], bfr[j], acc[i][j], 0, 0, 0);
    }
    __syncthreads();
  }
}

// ---------------------------------------------------------------------------
// QKV projection (bf16 in): z=0 -> Q*QSCALE [bh][s][d], z=1 -> K [bh][s][d],
// z=2 -> V^T [bh][d][s]. ONE m-tile per block (grid 64x8x3 = 1536): small
// blocks + many of them beat the 2-tile variant (R6: VGPR 140, occupancy 11%,
// +30us) — latency hiding needs block-level parallelism.
// ---------------------------------------------------------------------------
__global__ __launch_bounds__(256)
void gemm_qkv(const __hip_bfloat16* __restrict__ A,
              const __hip_bfloat16* __restrict__ W0, const float* __restrict__ b0, __hip_bfloat16* __restrict__ C0,
              const __hip_bfloat16* __restrict__ W1, const float* __restrict__ b1, __hip_bfloat16* __restrict__ C1,
              const __hip_bfloat16* __restrict__ W2, const float* __restrict__ b2, __hip_bfloat16* __restrict__ C2)
{
  __shared__ __hip_bfloat16 sA[128*64];
  __shared__ __hip_bfloat16 sB[128*64];
  const int z = blockIdx.z;
  const __hip_bfloat16* W = (z == 0) ? W0 : (z == 1) ? W1 : W2;
  const float* bias       = (z == 0) ? b0 : (z == 1) ? b1 : b2;
  __hip_bfloat16* C       = (z == 0) ? C0 : (z == 1) ? C1 : C2;

  const int tid = threadIdx.x, wid = tid >> 6, lane = tid & 63;
  const int wm = (wid >> 1) * 64, wn = (wid & 1) * 64;
  const int m16 = lane & 15, q = lane >> 4;
  const int tm = blockIdx.x * 128, tn = blockIdx.y * 128;

  floatx4 acc[4][4] = {};
  gemm_bf16_core(A, W, sA, sB, acc, tm, tn);

  if (z < 2) {
    const float sc = (z == 0) ? QSCALE : 1.0f;
    #pragma unroll
    for (int i = 0; i < 4; ++i)
      #pragma unroll
      for (int j = 0; j < 4; ++j)
        #pragma unroll
        for (int r = 0; r < 4; ++r) {
          int gm = tm + wm + i*16 + q*4 + r;     // token
          int gn = tn + wn + j*16 + m16;         // feature
          float v = (acc[i][j][r] + bias[gn]) * sc;
          int b = gm >> 11, s = gm & (SEQ - 1);
          int h = gn >> 6,  d = gn & (HD - 1);
          size_t bh = (size_t)(b*HEADS + h);
          C[(bh*SEQ + s)*HD + d] = __float2bfloat16(v);
        }
  } else {
    #pragma unroll
    for (int i = 0; i < 4; ++i)
      #pragma unroll
      for (int j = 0; j < 4; ++j) {
        int gm0 = tm + wm + i*16 + q*4;          // first token of quad
        int gn  = tn + wn + j*16 + m16;
        float bv = bias[gn];
        int b = gm0 >> 11, s0 = gm0 & (SEQ - 1);
        int h = gn >> 6,  d = gn & (HD - 1);
        size_t bh = (size_t)(b*HEADS + h);
        short4 pk;
        pk.x = f2bs(acc[i][j][0] + bv);
        pk.y = f2bs(acc[i][j][1] + bv);
        pk.z = f2bs(acc[i][j][2] + bv);
        pk.w = f2bs(acc[i][j][3] + bv);
        *(short4*)&C[(bh*HD + d)*SEQ + s0] = pk;  // V^T: 4 consecutive s
      }
  }
}

// ---------------------------------------------------------------------------
// Output projection: A (bf16 attn out) @ Wo^T + bo -> f32 d_out
// ---------------------------------------------------------------------------
__global__ __launch_bounds__(256)
void gemm_outp(const __hip_bfloat16* __restrict__ A,
               const __hip_bfloat16* __restrict__ W, const float* __restrict__ bias,
               float* __restrict__ C)
{
  __shared__ __hip_bfloat16 sA[128*64];
  __shared__ __hip_bfloat16 sB[128*64];
  const int tm = blockIdx.x * 128, tn = blockIdx.y * 128;
  floatx4 acc[4][4] = {};
  gemm_bf16_core(A, W, sA, sB, acc, tm, tn);
  const int tid = threadIdx.x, wid = tid >> 6, lane = tid & 63;
  const int wm = (wid >> 1) * 64, wn = (wid & 1) * 64;
  const int m16 = lane & 15, q = lane >> 4;
  #pragma unroll
  for (int i = 0; i < 4; ++i)
    #pragma unroll
    for (int j = 0; j < 4; ++j)
      #pragma unroll
      for (int r = 0; r < 4; ++r) {
        int gm = tm + wm + i*16 + q*4 + r;
        int gn = tn + wn + j*16 + m16;
        C[(size_t)gm*EMBD + gn] = acc[i][j][r] + bias[gn];
      }
}

// ---------------------------------------------------------------------------
// Flash attention, no-max softmax (scores bounded ~|2.5|; Q pre-scaled by
// log2(e)/8 so p = 2^score). Q-tile = 128 rows (2 q-sets of 16 per wave),
// Q fragments in registers, K/V^T double-buffered (one barrier per tile),
// V^T fragments register-hoisted & shared, l via ones-column MFMA, P packed
// by v_perm truncation into an XOR-swizzled unpadded sP.
// LDS = 40960 B -> 4 blocks/CU; grid 1024 -> single dispatch phase.
// Block index XCD-swizzled: all 16 q-tiles of one bh on one XCD.
// ---------------------------------------------------------------------------
__global__ __launch_bounds__(256)
void attn_fused(const __hip_bfloat16* __restrict__ Q,
                const __hip_bfloat16* __restrict__ Km,
                const __hip_bfloat16* __restrict__ Vt,
                __hip_bfloat16* __restrict__ O)
{
  __shared__ __hip_bfloat16 sK[2][64*64], sVT[2][64*64];
  __shared__ __hip_bfloat16 sP[4][16*64];
  const int tid = threadIdx.x, wid = tid >> 6, lane = tid & 63;
  const int m16 = lane & 15, g = lane >> 4;
  const int lr = lane >> 3;              // staging row-within-chunk
  const int lc = (lane & 7) ^ lr;        // swizzled source col16
  const int qt = (blockIdx.x >> 3) & 15;
  const int bh = (blockIdx.x & 7) | ((blockIdx.x >> 7) << 3);
  const int b = bh >> 4, h = bh & (HEADS - 1);
  const int swz = (m16 & 7);

  const __hip_bfloat16* Qb = Q  + ((size_t)bh*SEQ + qt*128) * HD;
  const __hip_bfloat16* Kb = Km + (size_t)bh*SEQ*HD;
  const __hip_bfloat16* Vb = Vt + (size_t)bh*HD*SEQ;

  // Q fragments straight from global (B-operand layout: n=m16, k=g*8+j)
  bf16x8 qf[2][2];
  #pragma unroll
  for (int u = 0; u < 2; ++u)
    #pragma unroll
    for (int ks = 0; ks < 2; ++ks)
      qf[u][ks] = *(const bf16x8*)(Qb + (size_t)(u*64 + wid*16 + m16)*HD + ks*32 + g*8);

  bf16x8 onesf;
  #pragma unroll
  for (int i = 0; i < 8; ++i) onesf[i] = (short)0x3F80;   // bf16 1.0

  floatx4 o_acc[2][4] = {};
  floatx4 lacc[2] = {};

  #define STAGE(KT, BUF)                                                     \
    { int _c = wid*2;                                                        \
      _Pragma("unroll")                                                      \
      for (int c2 = 0; c2 < 2; ++c2) {                                       \
        int c = _c + c2, row = c*8 + lr;                                     \
        async16(Kb + (size_t)((KT)*64 + row)*HD + lc*8, sK[BUF] + c*512);    \
        async16(Vb + (size_t)row*SEQ + (KT)*64 + lc*8,  sVT[BUF] + c*512);   \
      } }

  STAGE(0, 0)

  for (int kt = 0; kt < SEQ/64; ++kt) {
    const int cur = kt & 1;
    __syncthreads();                 // drains prefetch(kt); guards buf reuse
    if (kt < SEQ/64 - 1) STAGE(kt + 1, cur ^ 1)

    // hoist V^T fragments (shared by both q-sets)
    bf16x8 vtf[2][4];
    #pragma unroll
    for (int ks = 0; ks < 2; ++ks)
      #pragma unroll
      for (int dt = 0; dt < 4; ++dt)
        vtf[ks][dt] = *(const bf16x8*)&sVT[cur][(dt*16 + m16)*64 + ((ks*4 + g) ^ swz)*8];

    // S^T for both q-sets, sharing K fragment loads
    floatx4 st[2][4] = {};
    #pragma unroll
    for (int ks = 0; ks < 2; ++ks) {
      #pragma unroll
      for (int nt = 0; nt < 4; ++nt) {
        bf16x8 kf = *(const bf16x8*)&sK[cur][(nt*16 + m16)*64 + ((ks*4 + g) ^ swz)*8];
        st[0][nt] = __builtin_amdgcn_mfma_f32_16x16x32_bf16(kf, qf[0][ks], st[0][nt], 0, 0, 0);
        st[1][nt] = __builtin_amdgcn_mfma_f32_16x16x32_bf16(kf, qf[1][ks], st[1][nt], 0, 0, 0);
      }
    }

    // per q-set: exp, pack, swizzled-sP round-trip, PV + l
    #pragma unroll
    for (int u = 0; u < 2; ++u) {
      #pragma unroll
      for (int nt = 0; nt < 4; ++nt) {
        float p0 = __builtin_amdgcn_exp2f(st[u][nt][0]);
        float p1 = __builtin_amdgcn_exp2f(st[u][nt][1]);
        float p2 = __builtin_amdgcn_exp2f(st[u][nt][2]);
        float p3 = __builtin_amdgcn_exp2f(st[u][nt][3]);
        uint2 pu;
        pu.x = pack_trunc(p0, p1);
        pu.y = pack_trunc(p2, p3);
        // data cols nt*16+g*4..+3 -> chunk = nt*2 + (g>>1), half = g&1
        *(uint2*)&sP[wid][m16*64 + (((nt*2 + (g>>1)) ^ swz)*8) + (g&1)*4] = pu;
      }
      #pragma unroll
      for (int ks = 0; ks < 2; ++ks) {
        // data cols ks*32+g*8..+7 -> chunk = ks*4 + g
        bf16x8 af = *(const bf16x8*)&sP[wid][m16*64 + ((ks*4 + g) ^ swz)*8];
        lacc[u] = __builtin_amdgcn_mfma_f32_16x16x32_bf16(af, onesf, lacc[u], 0, 0, 0);
        #pragma unroll
        for (int dt = 0; dt < 4; ++dt)
          o_acc[u][dt] = __builtin_amdgcn_mfma_f32_16x16x32_bf16(af, vtf[ks][dt], o_acc[u][dt], 0, 0, 0);
      }
    }
  }

  // epilogue: normalize, store [token][emb]
  #pragma unroll
  for (int u = 0; u < 2; ++u) {
    float inv[4];
    #pragma unroll
    for (int r = 0; r < 4; ++r) inv[r] = 1.0f / lacc[u][r];
    #pragma unroll
    for (int dt = 0; dt < 4; ++dt)
      #pragma unroll
      for (int r = 0; r < 4; ++r) {
        int s = qt*128 + u*64 + wid*16 + g*4 + r;
        int d = dt*16 + m16;
        float v = o_acc[u][dt][r] * inv[r];
        O[((size_t)(b*SEQ + s))*EMBD + h*HD + d] = __float2bfloat16(v);
      }
  }
}

// ---------------------------------------------------------------------------
extern "C" void kernel_launch(void* const* d_in, const int* in_sizes, int n_in,
                              void* d_out, int out_size, void* d_ws, size_t ws_size,
                              hipStream_t stream) {
  const float* emb = (const float*)d_in[0];
  const float* Wq  = (const float*)d_in[1];
  const float* bq  = (const float*)d_in[2];
  const float* Wk  = (const float*)d_in[3];
  const float* bk  = (const float*)d_in[4];
  const float* Wv  = (const float*)d_in[5];
  const float* bv  = (const float*)d_in[6];
  const float* Wo  = (const float*)d_in[7];
  const float* bo  = (const float*)d_in[8];

  const size_t T = (size_t)NTOK*EMBD;     // 8388608
  const size_t WN = (size_t)EMBD*EMBD;    // 1048576
  __hip_bfloat16* Qw  = (__hip_bfloat16*)d_ws;   // [bh][s][d], pre-scaled
  __hip_bfloat16* Kw  = Qw + T;                  // [bh][s][d]
  __hip_bfloat16* Vw  = Kw + T;                  // [bh][d][s]
  __hip_bfloat16* Aw  = Vw + T;                  // attn out [token][emb]; embB aliases (emb dead after qkv)
  __hip_bfloat16* embB = Aw;
  __hip_bfloat16* WqB = Aw + T;
  __hip_bfloat16* WkB = WqB + WN;
  __hip_bfloat16* WvB = WkB + WN;
  __hip_bfloat16* WoB = WvB + WN;
  float* Ob = (float*)d_out;

  precast<<<dim3(6144), 256, 0, stream>>>(emb, Wq, Wk, Wv, Wo,
                                          embB, WqB, WkB, WvB, WoB);

  dim3 gq(NTOK/128, EMBD/128, 3);
  gemm_qkv<<<gq, 256, 0, stream>>>(embB, WqB, bq, Qw, WkB, bk, Kw, WvB, bv, Vw);

  attn_fused<<<dim3(64*16), 256, 0, stream>>>(Qw, Kw, Vw, Aw);

  dim3 go(NTOK/128, EMBD/128);
  gemm_outp<<<go, 256, 0, stream>>>(Aw, WoB, bo, Ob);
}